// Round 13
// baseline (1445.869 us; speedup 1.0000x reference)
//
#include <hip/hip_runtime.h>

#define HH 128
#define WW 128
#define HWP (HH*WW)
#define NC 64
#define NB 2
#define NN 5
#define OFFC 144
#define NKC 18                    // K-chunks of 32 per 576-K conv pass
#define DKC 24                    // deform K-chunks (8 rounds x 3)

typedef __attribute__((ext_vector_type(8))) _Float16 half8;
typedef __attribute__((ext_vector_type(4))) float floatx4;
typedef __attribute__((ext_vector_type(2))) float floatx2;

// out[b, center=2] = x_center
__global__ __launch_bounds__(256) void copy_center_k(const float* __restrict__ xc,
                                                     float* __restrict__ out) {
    int idx = blockIdx.x * 256 + threadIdx.x;
    const int total = NB * 3 * HWP;
    if (idx >= total) return;
    int b = idx / (3 * HWP);
    int r = idx - b * 3 * HWP;
    out[(size_t)((b * NN + 2) * 3) * HWP + r] = xc[idx];
}

// Repack planar pf frame -> channel-last [px][64]. is_ref: blockIdx.y = b (center frame);
// else blockIdx.y = jl (supp frame of job job0+jl). LDS 64x65 transpose tile.
__global__ __launch_bounds__(256) void repack_k(const float* __restrict__ pf,
                                                float* __restrict__ dst, int job0, int is_ref)
{
    __shared__ float T[64][65];
    const int jl = blockIdx.y;
    const float* src;
    if (is_ref) {
        src = pf + (size_t)((jl * NN + 2) * NC) * HWP;
    } else {
        int jg = job0 + jl;
        int b = jg & 1, fi = jg >> 1;
        int frame = fi + (fi >= 2 ? 1 : 0);
        src = pf + (size_t)((b * NN + frame) * NC) * HWP;
    }
    float* d = dst + (size_t)jl * NC * HWP;
    const int p0 = blockIdx.x * 64;
    const int tid = threadIdx.x;
    const int lx = tid & 63, cg4 = tid >> 6;
#pragma unroll
    for (int cc = 0; cc < 16; ++cc) {
        int c = cc * 4 + cg4;
        T[c][lx] = src[(size_t)c * HWP + p0 + lx];
    }
    __syncthreads();
    const int px = tid >> 2, c0 = (tid & 3) * 16;
#pragma unroll
    for (int j = 0; j < 4; ++j) {
        floatx4 v = { T[c0 + j*4 + 0][px], T[c0 + j*4 + 1][px],
                      T[c0 + j*4 + 2][px], T[c0 + j*4 + 3][px] };
        *(floatx4*)(d + (size_t)(p0 + px) * 64 + c0 + j*4) = v;
    }
}

// Weight preprocessor, SPLIT-fp16: w[co][cin_src][9] -> wp[ct][kc][{hi,lo}][lane][8],
// k = kc*32 + (lane>>4)*8 + j.
// mode 0 (conv, nkc=18):   kk = k>>6, ci = k&63 (+ci_off).
// mode 1 (deform, nkc=24): r = k/96, kr = k%96; kr<72: g = r, kk = kr>>3, cg = kr&7,
//                          ci = g*8+cg; else zero pad (8 rounds x 1 group, K 72->96).
__global__ __launch_bounds__(256) void prew_k(const float* __restrict__ w,
                                              _Float16* __restrict__ wp,
                                              int nct, int nkc, int mode,
                                              int ci_off, int cin_src)
{
    int idx = blockIdx.x * 256 + threadIdx.x;
    if (idx >= nct * nkc * 64) return;
    int lane = idx & 63;
    int kc = (idx >> 6) % nkc;
    int ct = (idx >> 6) / nkc;
    int m = lane & 15, quad = lane >> 4;
    int co = ct * 16 + m;
    union { half8 v; _Float16 e[8]; } ph, pl;
#pragma unroll
    for (int j = 0; j < 8; ++j) {
        int k = kc * 32 + quad * 8 + j;
        float f = 0.f;
        if (mode == 0) {
            int kk = k >> 6, ci = k & 63;
            f = w[((size_t)co * cin_src + ci_off + ci) * 9 + kk];
        } else {
            int r = k / 96, kr = k - r * 96;
            if (kr < 72) {
                int kk = kr >> 3, cg = kr & 7;
                f = w[((size_t)co * cin_src + r * 8 + cg) * 9 + kk];
            }
        }
        _Float16 h = (_Float16)f;
        ph.e[j] = h; pl.e[j] = (_Float16)(f - (float)h);
    }
    size_t base = (size_t)((ct * nkc + kc) * 2) * 512;
    *(half8*)(wp + base + lane * 8) = ph.v;
    *(half8*)(wp + base + 512 + lane * 8) = pl.v;
}

// SPLIT-fp16 MFMA 3x3 conv, CHANNEL-LAST src & dst. Unchanged from R11/R12 (proven):
// kc outer / ct inner, B-rows read once per kc, A-frags streamed JIT from L2.
template<int NCT, int SRCMODE, int ADD>
__global__ __launch_bounds__(256, 3) void mconv_k(
    const float* __restrict__ src, const float* __restrict__ R,
    const float* __restrict__ S, const _Float16* __restrict__ wp,
    const float* __restrict__ bias, float* __restrict__ out, int job0)
{
    constexpr int PL = 1456;              // 10*18*8 = 1440 + 16 pad (fp16 elems)
    constexpr int Ct = NCT * 16;
    const int jl = blockIdx.y, jg = job0 + jl;
    const int b = jg & 1;
    const int tile = blockIdx.x;          // 8 in x, 16 in y
    const int ty0 = (tile >> 3) << 3, tx0 = (tile & 7) << 4;
    const int tid = threadIdx.x;
    const int lane = tid & 63;
    const int wq = __builtin_amdgcn_readfirstlane(tid >> 6);
    const int n = lane & 15, quad = lane >> 4;

    const float* s0;
    if (SRCMODE == 0)      s0 = src + (size_t)jl * NC * HWP;
    else if (SRCMODE == 1) s0 = R + (size_t)b * NC * HWP;
    else                   s0 = S + (size_t)jl * NC * HWP;

    __shared__ _Float16 hh[8 * PL];
    __shared__ _Float16 ll[8 * PL];

    for (int t = tid; t < 360; t += 256) {
        int px = t >> 1, hf = t & 1;
        int hy = px / 18, hx = px - hy * 18;
        int gy = ty0 - 1 + hy, gx = tx0 - 1 + hx;
        bool ok = (gy >= 0 && gy < HH && gx >= 0 && gx < WW);
        const float* sp = s0 + (ok ? ((size_t)(gy * WW + gx) * 64) : 0) + hf * 32;
        int lb = px * 8;
#pragma unroll
        for (int c = 0; c < 4; ++c) {
            int cb = hf * 4 + c;
            floatx4 f0 = {0.f,0.f,0.f,0.f}, f1 = {0.f,0.f,0.f,0.f};
            if (ok) {
                f0 = *(const floatx4*)(sp + c * 8);
                f1 = *(const floatx4*)(sp + c * 8 + 4);
            }
            union { half8 v; _Float16 e[8]; } ph, pl;
#pragma unroll
            for (int j = 0; j < 4; ++j) {
                _Float16 h0 = (_Float16)f0[j], h1 = (_Float16)f1[j];
                ph.e[j] = h0;     ph.e[j+4] = h1;
                pl.e[j] = (_Float16)(f0[j] - (float)h0);
                pl.e[j+4] = (_Float16)(f1[j] - (float)h1);
            }
            *(half8*)&hh[cb * PL + lb] = ph.v;
            *(half8*)&ll[cb * PL + lb] = pl.v;
        }
    }
    __syncthreads();

    floatx4 acc0[NCT], acc1[NCT];
#pragma unroll
    for (int ct = 0; ct < NCT; ++ct) {
        acc0[ct] = floatx4{0.f, 0.f, 0.f, 0.f};
        acc1[ct] = floatx4{0.f, 0.f, 0.f, 0.f};
    }
    const int y0 = wq * 2, y1 = y0 + 1;
#pragma unroll
    for (int kc = 0; kc < NKC; ++kc) {
        const int kk = kc >> 1;
        const int dy = kk / 3, dx = kk % 3;
        const int cb = ((kc & 1) << 2) + quad;
        const int ix0 = cb * PL + ((y0 + dy) * 18 + n + dx) * 8;
        const int ix1 = cb * PL + ((y1 + dy) * 18 + n + dx) * 8;
        half8 B0h = *(const half8*)&hh[ix0];
        half8 B0l = *(const half8*)&ll[ix0];
        half8 B1h = *(const half8*)&hh[ix1];
        half8 B1l = *(const half8*)&ll[ix1];
        const _Float16* wk = wp + (size_t)kc * 1024 + lane * 8;
#pragma unroll
        for (int ct = 0; ct < NCT; ++ct) {
            const _Float16* wc = wk + (size_t)ct * NKC * 1024;
            half8 Ah = *(const half8*)wc;
            half8 Al = *(const half8*)(wc + 512);
            acc0[ct] = __builtin_amdgcn_mfma_f32_16x16x32_f16(Ah, B0h, acc0[ct], 0, 0, 0);
            acc0[ct] = __builtin_amdgcn_mfma_f32_16x16x32_f16(Ah, B0l, acc0[ct], 0, 0, 0);
            acc0[ct] = __builtin_amdgcn_mfma_f32_16x16x32_f16(Al, B0h, acc0[ct], 0, 0, 0);
            acc1[ct] = __builtin_amdgcn_mfma_f32_16x16x32_f16(Ah, B1h, acc1[ct], 0, 0, 0);
            acc1[ct] = __builtin_amdgcn_mfma_f32_16x16x32_f16(Ah, B1l, acc1[ct], 0, 0, 0);
            acc1[ct] = __builtin_amdgcn_mfma_f32_16x16x32_f16(Al, B1h, acc1[ct], 0, 0, 0);
        }
    }

    const int oy0 = ty0 + y0, oy1 = ty0 + y1, ox = tx0 + n;
#pragma unroll
    for (int ct = 0; ct < NCT; ++ct) {
        const floatx4 b4 = *(const floatx4*)(bias + ct * 16 + quad * 4);
        float* op0 = out + ((size_t)jl * HWP + (size_t)oy0 * WW + ox) * Ct
                         + ct * 16 + quad * 4;
        float* op1 = out + ((size_t)jl * HWP + (size_t)oy1 * WW + ox) * Ct
                         + ct * 16 + quad * 4;
        floatx4 v0 = acc0[ct], v1 = acc1[ct];
        if (ADD) {
            v0 += *(const floatx4*)op0;
            v1 += *(const floatx4*)op1;
        } else {
            v0 += b4;
            v1 += b4;
        }
        *(floatx4*)op0 = v0;
        *(floatx4*)op1 = v1;
    }
}

// Deformable conv, MFMA phase B (split-fp16), lane-paired gathers (R12-proven).
// R13: 8 rounds x 1 group (was 4x2) -> LDS halved (SROW 166->102, 42.5->26.1 KB)
// -> 6 blocks/CU (was 3). SROW=102: 51 dwords/row, 51%32==83%32=19 -> banking
// identical to the proven 166 layout. K per round 72 padded to 96 (3 chunks);
// pad cols [72,96) zeroed once (phase A never writes them). +20% MFMA (9%-busy pipe).
__global__ __launch_bounds__(256, 6) void mdeform_k(
    const float* __restrict__ in, const float* __restrict__ off,
    const _Float16* __restrict__ wp, const float* __restrict__ bias,
    float* __restrict__ out, int supp_mode, const float* __restrict__ S)
{
    constexpr int SROW = 102;
    const int jl = blockIdx.y;
    const int tile = blockIdx.x;          // 16x16 tiles of 8x8
    const int ty0 = (tile >> 4) << 3, tx0 = (tile & 15) << 3;
    const int tid = threadIdx.x;
    const int lane = tid & 63;
    const int q = __builtin_amdgcn_readfirstlane(tid >> 6);
    const int n = lane & 15, quad = lane >> 4;

    const float* ibase = supp_mode ? (S + (size_t)jl * NC * HWP)
                                   : (in + (size_t)jl * NC * HWP);
    const float* obase = off + (size_t)jl * OFFC * HWP;

    __shared__ _Float16 sh[64 * SROW];
    __shared__ _Float16 sl[64 * SROW];

    // zero pad K-slots [72,96) once (phase A only writes cols 0..71)
    for (int e = tid; e < 64 * 24; e += 256) {
        int row = e / 24, col = 72 + (e % 24);
        sh[row * SROW + col] = (_Float16)0.f;
        sl[row * SROW + col] = (_Float16)0.f;
    }

    floatx4 acc[4];
#pragma unroll
    for (int s = 0; s < 4; ++s) acc[s] = floatx4{0.f, 0.f, 0.f, 0.f};

    for (int r = 0; r < 8; ++r) {
        __syncthreads();
        // ---- phase A: lane-paired. 1152 lane-tasks = 2 x (9 kk x 64 px), group g=r
        for (int tk = tid; tk < 1152; tk += 256) {
            int hf = tk & 1;                  // which 4-channel half of the group
            int pair = tk >> 1;               // 0..575
            int kk = pair >> 6;
            int px = pair & 63;
            int yy = ty0 + (px >> 3), xx = tx0 + (px & 7);
            floatx2 o2 = *(const floatx2*)(obase + (size_t)(yy * WW + xx) * OFFC
                                           + (r * 9 + kk) * 2);
            float pyf = (float)(yy + (kk / 3) - 1) + o2[0];
            float pxf = (float)(xx + (kk % 3) - 1) + o2[1];
            float fy = floorf(pyf), fx = floorf(pxf);
            float wy = pyf - fy, wx = pxf - fx;
            int y0 = (int)fy, x0 = (int)fx;
            int y1 = y0 + 1, x1 = x0 + 1;
            float m00 = (y0 >= 0 && y0 < HH && x0 >= 0 && x0 < WW) ? 1.f : 0.f;
            float m01 = (y0 >= 0 && y0 < HH && x1 >= 0 && x1 < WW) ? 1.f : 0.f;
            float m10 = (y1 >= 0 && y1 < HH && x0 >= 0 && x0 < WW) ? 1.f : 0.f;
            float m11 = (y1 >= 0 && y1 < HH && x1 >= 0 && x1 < WW) ? 1.f : 0.f;
            float w00 = (1.f - wy) * (1.f - wx) * m00;
            float w01 = (1.f - wy) * wx * m01;
            float w10 = wy * (1.f - wx) * m10;
            float w11 = wy * wx * m11;
            int cy0 = min(max(y0, 0), HH - 1), cy1 = min(max(y1, 0), HH - 1);
            int cx0 = min(max(x0, 0), WW - 1), cx1 = min(max(x1, 0), WW - 1);
            const int co = r * 8 + hf * 4;    // channel offset of this lane's half
            const float* p00 = ibase + (size_t)(cy0 * WW + cx0) * 64 + co;
            const float* p01 = ibase + (size_t)(cy0 * WW + cx1) * 64 + co;
            const float* p10 = ibase + (size_t)(cy1 * WW + cx0) * 64 + co;
            const float* p11 = ibase + (size_t)(cy1 * WW + cx1) * 64 + co;
            floatx4 a = *(const floatx4*)p00;
            floatx4 b = *(const floatx4*)p01;
            floatx4 c = *(const floatx4*)p10;
            floatx4 d = *(const floatx4*)p11;
            floatx4 sv = a * w00 + b * w01 + c * w10 + d * w11;
            union { unsigned u[2]; _Float16 e[4]; } P, L;
#pragma unroll
            for (int j = 0; j < 4; ++j) {
                _Float16 h = (_Float16)sv[j];
                P.e[j] = h;
                L.e[j] = (_Float16)(sv[j] - (float)h);
            }
            int sb = px * SROW + kk * 8 + hf * 4;   // even -> 4-B aligned
            unsigned* shp = (unsigned*)&sh[sb];
            unsigned* slp = (unsigned*)&sl[sb];
            shp[0] = P.u[0]; shp[1] = P.u[1];
            slp[0] = L.u[0]; slp[1] = L.u[1];
        }
        __syncthreads();
        // ---- phase B: MFMA contraction, wave q -> co-tile q ----
#pragma unroll
        for (int kc3 = 0; kc3 < 3; ++kc3) {
            int kcg = r * 3 + kc3;
            size_t base = (size_t)((q * DKC + kcg) * 2) * 512;
            half8 Ah = *(const half8*)(wp + base + lane * 8);
            half8 Al = *(const half8*)(wp + base + 512 + lane * 8);
#pragma unroll
            for (int s = 0; s < 4; ++s) {
                int px = s * 16 + n;
                const int ix = px * SROW + kc3 * 32 + quad * 8;
                half8 Bh = *(const half8*)&sh[ix];
                half8 Bl = *(const half8*)&sl[ix];
                acc[s] = __builtin_amdgcn_mfma_f32_16x16x32_f16(Ah, Bh, acc[s], 0, 0, 0);
                acc[s] = __builtin_amdgcn_mfma_f32_16x16x32_f16(Ah, Bl, acc[s], 0, 0, 0);
                acc[s] = __builtin_amdgcn_mfma_f32_16x16x32_f16(Al, Bh, acc[s], 0, 0, 0);
            }
        }
    }
    const floatx4 b4 = *(const floatx4*)(bias + q * 16 + quad * 4);
#pragma unroll
    for (int s = 0; s < 4; ++s) {
        int px = s * 16 + n;
        int oy = ty0 + (px >> 3), ox = tx0 + (px & 7);
        float* op = out + ((size_t)jl * HWP + (size_t)oy * WW + ox) * 64
                        + q * 16 + quad * 4;
        *(floatx4*)op = acc[s] + b4;
    }
}

// rec conv (64 -> 3): fp32, channel-last input. Writes d_out (planar).
__global__ __launch_bounds__(256) void conv3x3_rec_k(
    const float* __restrict__ in, const float* __restrict__ w,
    const float* __restrict__ bias, float* __restrict__ out, int job0)
{
    constexpr int CB = 8;
    constexpr int PITCH = 48;
    constexpr int CH = 18 * PITCH;
    const int jl = blockIdx.y, jg = job0 + jl;
    const int b = jg & 1, fi = jg >> 1;
    const int frame = fi + (fi >= 2 ? 1 : 0);
    const int tile = blockIdx.x;
    const int ty0 = (tile >> 3) << 4, tx0 = (tile & 7) << 4;
    const int tid = threadIdx.x;
    const int tx = tid & 15, ty = tid >> 4;
    const float* srcA = in + (size_t)jl * NC * HWP;

    __shared__ float lds[CB * CH];
    float acc[3] = {bias[0], bias[1], bias[2]};

    for (int cb = 0; cb < NC; cb += CB) {
        __syncthreads();
        for (int e = tid; e < CB * 324; e += 256) {
            int c = e & 7;
            int r = e >> 3;
            int iy = r / 18, ix = r - iy * 18;
            int gy = ty0 - 1 + iy, gx = tx0 - 1 + ix;
            float v = 0.f;
            if (gy >= 0 && gy < HH && gx >= 0 && gx < WW)
                v = srcA[(size_t)(gy * WW + gx) * 64 + cb + c];
            lds[c * CH + iy * PITCH + ix] = v;
        }
        __syncthreads();
#pragma unroll
        for (int c = 0; c < CB; ++c) {
            float t[9];
#pragma unroll
            for (int dy = 0; dy < 3; ++dy)
#pragma unroll
                for (int dx = 0; dx < 3; ++dx)
                    t[dy * 3 + dx] = lds[c * CH + (ty + dy) * PITCH + (tx + dx)];
            int ci = cb + c;
#pragma unroll
            for (int o = 0; o < 3; ++o) {
                const float* wo = w + ((size_t)o * NC + ci) * 9;
#pragma unroll
                for (int kk = 0; kk < 9; ++kk)
                    acc[o] = fmaf(wo[kk], t[kk], acc[o]);
            }
        }
    }
    const int oy = ty0 + ty, ox = tx0 + tx;
#pragma unroll
    for (int o = 0; o < 3; ++o)
        out[((size_t)(b * NN + frame) * 3 + o) * HWP + oy * WW + ox] = acc[o];
}

extern "C" void kernel_launch(void* const* d_in, const int* in_sizes, int n_in,
                              void* d_out, int out_size, void* d_ws, size_t ws_size,
                              hipStream_t stream)
{
    const float* pf    = (const float*)d_in[0];
    const float* xc    = (const float*)d_in[1];
    const float* cr_w  = (const float*)d_in[2];
    const float* cr_b  = (const float*)d_in[3];
    const float* ow[4] = {(const float*)d_in[4],  (const float*)d_in[8],
                          (const float*)d_in[12], (const float*)d_in[16]};
    const float* ob[4] = {(const float*)d_in[5],  (const float*)d_in[9],
                          (const float*)d_in[13], (const float*)d_in[17]};
    const float* dw[4] = {(const float*)d_in[6],  (const float*)d_in[10],
                          (const float*)d_in[14], (const float*)d_in[18]};
    const float* db[4] = {(const float*)d_in[7],  (const float*)d_in[11],
                          (const float*)d_in[15], (const float*)d_in[19]};
    const float* rec_w = (const float*)d_in[20];
    const float* rec_b = (const float*)d_in[21];
    float* out = (float*)d_out;

    // ws layout: [wp cr x2][wp of x4][wp dc x4][R 2][S JC][A JC][Bb JC][O JC]
    const size_t WPC = (size_t)4 * NKC * 1024;
    const size_t WPO = (size_t)9 * NKC * 1024;
    const size_t WPD = (size_t)4 * DKC * 1024;
    _Float16* wp_cr0 = (_Float16*)d_ws;
    _Float16* wp_cr1 = wp_cr0 + WPC;
    _Float16* wp_of[4];
    _Float16* wp_dc[4];
    _Float16* curh = wp_cr1 + WPC;
    for (int i = 0; i < 4; ++i) { wp_of[i] = curh; curh += WPO; }
    for (int i = 0; i < 4; ++i) { wp_dc[i] = curh; curh += WPD; }
    size_t wp_bytes = (size_t)((char*)curh - (char*)d_ws);

    const size_t fplane = (size_t)NC * HWP;
    const size_t oplane = (size_t)OFFC * HWP;
    int JC = 8;
    while (JC > 1 &&
           wp_bytes + (2 + 3 * (size_t)JC) * fplane * 4 + (size_t)JC * oplane * 4 > ws_size)
        JC >>= 1;
    float* R  = (float*)curh;
    float* S  = R  + 2 * fplane;
    float* A  = S  + (size_t)JC * fplane;
    float* Bb = A  + (size_t)JC * fplane;
    float* O  = Bb + (size_t)JC * fplane;

    // ---- weight preprocessing + ref repack (every call; ws re-poisoned) ----
    {
        int nc4 = 4 * NKC * 64, nc9 = 9 * NKC * 64, ncd = 4 * DKC * 64;
        dim3 b4((nc4 + 255) / 256), b9((nc9 + 255) / 256), bd((ncd + 255) / 256);
        prew_k<<<b4, 256, 0, stream>>>(cr_w, wp_cr0, 4, NKC, 0, 0, 128);
        prew_k<<<b4, 256, 0, stream>>>(cr_w, wp_cr1, 4, NKC, 0, 64, 128);
        for (int i = 0; i < 4; ++i) {
            prew_k<<<b9, 256, 0, stream>>>(ow[i], wp_of[i], 9, NKC, 0, 0, 64);
            prew_k<<<bd, 256, 0, stream>>>(dw[i], wp_dc[i], 4, DKC, 1, 0, 64);
        }
        repack_k<<<dim3(256, 2), 256, 0, stream>>>(pf, R, 0, 1);
    }

    copy_center_k<<<dim3((NB * 3 * HWP + 255) / 256), 256, 0, stream>>>(xc, out);

    for (int job0 = 0; job0 < 8; job0 += JC) {
        dim3 blk(256);
        dim3 gconv(128, JC), gdef(256, JC), grec(64, JC);
        repack_k<<<dim3(256, JC), blk, 0, stream>>>(pf, S, job0, 0);
        // fea1 = cr_conv(concat(ref, supp)) : two K=576 passes (ref, then supp ADD)
        mconv_k<4, 1, 0><<<gconv, blk, 0, stream>>>(nullptr, R, S, wp_cr0, cr_b, A, job0);
        mconv_k<4, 2, 1><<<gconv, blk, 0, stream>>>(nullptr, R, S, wp_cr1, cr_b, A, job0);
        // off1(fea1); fea2 = deform(fea1)
        mconv_k<9, 0, 0><<<gconv, blk, 0, stream>>>(A, R, S, wp_of[0], ob[0], O, job0);
        mdeform_k<<<gdef, blk, 0, stream>>>(A, O, wp_dc[0], db[0], Bb, 0, S);
        // off2(fea2); fea3 = deform(fea2)
        mconv_k<9, 0, 0><<<gconv, blk, 0, stream>>>(Bb, R, S, wp_of[1], ob[1], O, job0);
        mdeform_k<<<gdef, blk, 0, stream>>>(Bb, O, wp_dc[1], db[1], A, 0, S);
        // off3(fea3); fea4 = deform(supp)
        mconv_k<9, 0, 0><<<gconv, blk, 0, stream>>>(A, R, S, wp_of[2], ob[2], O, job0);
        mdeform_k<<<gdef, blk, 0, stream>>>(nullptr, O, wp_dc[2], db[2], Bb, 1, S);
        // off4(fea4); aligned = deform(fea4)
        mconv_k<9, 0, 0><<<gconv, blk, 0, stream>>>(Bb, R, S, wp_of[3], ob[3], O, job0);
        mdeform_k<<<gdef, blk, 0, stream>>>(Bb, O, wp_dc[3], db[3], A, 0, S);
        // out[b, frame] = rec_conv(aligned)
        conv3x3_rec_k<<<grec, blk, 0, stream>>>(A, rec_w, rec_b, out, job0);
    }
}